// Round 5
// baseline (266.869 us; speedup 1.0000x reference)
//
#include <hip/hip_runtime.h>
#include <hip/hip_bf16.h>
#include <stdint.h>

#define B_   4096
#define IN_  1024
#define H_   1024
#define OUT_ 1024

typedef __attribute__((ext_vector_type(8)))  short short8;
typedef __attribute__((ext_vector_type(16))) float floatx16;

// ---------- async global->LDS (16B per lane; LDS base wave-uniform, HW adds lane*16) ----------
__device__ static inline void gload_lds16(const void* g, void* l) {
    __builtin_amdgcn_global_load_lds(
        (const __attribute__((address_space(1))) unsigned int*)g,
        (__attribute__((address_space(3))) unsigned int*)l,
        16, 0, 0);
}

__device__ static inline float sigmoidf_(float x) { return 1.0f / (1.0f + __expf(-x)); }
__device__ static inline float tanhf_(float x)    { return 1.0f - 2.0f / (1.0f + __expf(2.0f * x)); }

// ---------- merged conversion kernel ----------
// blocks [0,8192):    xh[b][c] = bf16(c<1024 ? x[b][c] : h[b][c-1024])        [4096][2048]
// blocks [8192,16384): Wc gate interleaved period 64: n = (h>>4)*64 + gate*16 + (h&15)
// blocks [16384,17408): Wob = bf16(W_out)                                     [1024][1024]
struct Ptrs8 { const float* p[8]; };

__global__ void cvt_all_kernel(const float* __restrict__ x, const float* __restrict__ h,
                               Ptrs8 ptrs, const float* __restrict__ wout,
                               __hip_bfloat16* __restrict__ xh,
                               __hip_bfloat16* __restrict__ Wc,
                               __hip_bfloat16* __restrict__ Wob) {
    int blk = blockIdx.x;
    const float* src;
    __hip_bfloat16* dst;
    if (blk < 8192) {
        int idx = blk * 256 + threadIdx.x;          // B*512
        int b  = idx >> 9;
        int c4 = (idx & 511) * 4;
        src = (c4 < IN_) ? (x + (size_t)b * IN_ + c4)
                         : (h + (size_t)b * H_ + (c4 - IN_));
        dst = xh + (size_t)b * 2048 + c4;
    } else if (blk < 16384) {
        int idx = (blk - 8192) * 256 + threadIdx.x; // 4096*512
        int n  = idx >> 9;
        int c4 = (idx & 511) * 4;
        int gate = (n >> 4) & 3;
        int hh   = ((n >> 6) << 4) + (n & 15);
        src = (c4 < 1024) ? (ptrs.p[2 * gate]     + (size_t)hh * 1024 + c4)
                          : (ptrs.p[2 * gate + 1] + (size_t)hh * 1024 + (c4 - 1024));
        dst = Wc + (size_t)n * 2048 + c4;
    } else {
        int idx = (blk - 16384) * 256 + threadIdx.x;
        src = wout + (size_t)idx * 4;
        dst = Wob + (size_t)idx * 4;
    }
    float4 v = *(const float4*)src;
    dst[0] = __float2bfloat16(v.x);
    dst[1] = __float2bfloat16(v.y);
    dst[2] = __float2bfloat16(v.z);
    dst[3] = __float2bfloat16(v.w);
}

// ---------- gate GEMM + fused LSTM epilogue ----------
// A = xh [4096][2048], Bm = Wc [4096][2048] (gate interleave period 64).
// Block tile 128x128, BK=64, 4 waves each 64x64 (acc[2][2] of 32x32x16).
// 1024 blocks -> 4/CU (LDS 32KB, VGPR ~110). XOR chunk swizzle on LDS.
// Epilogue: within a wave's 64 cols, lane fr holds gates {f,o} (fr<16) or {i,g}
// (fr>=16) of h = (n0+wcol)/64*16 + (fr&15); partner lane^16 holds the other
// pair of the SAME h -> one shfl_xor(16) per acc element completes the gate set.
__global__ __launch_bounds__(256, 4) void gemm_gate_fused(
    const __hip_bfloat16* __restrict__ A,
    const __hip_bfloat16* __restrict__ Bm,
    const float* __restrict__ cell,
    const float* __restrict__ bxf, const float* __restrict__ bxi,
    const float* __restrict__ bxo, const float* __restrict__ bxg,
    float* __restrict__ new_hidden, float* __restrict__ new_cell,
    __hip_bfloat16* __restrict__ hb)
{
    constexpr int BK = 64;
    constexpr int K  = 2048;

    __shared__ __hip_bfloat16 ldsA[128 * BK];   // 16 KB
    __shared__ __hip_bfloat16 ldsB[128 * BK];   // 16 KB

    const int tid  = threadIdx.x;
    const int lane = tid & 63;
    const int wv   = tid >> 6;

    // XCD swizzle: xcd = bid&7 owns n-tiles [xcd*4, xcd*4+4) (2MB Wc stripe -> its L2).
    const int bid    = blockIdx.x;             // 1024 blocks
    const int xcd    = bid & 7;
    const int loc    = bid >> 3;               // 0..127
    const int n_tile = xcd * 4 + (loc & 3);    // 0..31
    const int m_tile = loc >> 2;               // 0..31
    const int m0 = m_tile * 128;
    const int n0 = n_tile * 128;

    // staging gather: thread tid fills LDS slot tid*16 (+s*4096 per issue);
    // row = s*32 + tid/8, stored chunk = tid%8 -> fetch global chunk (tid%8)^(row&7)
    const int srow   = tid >> 3;
    const int schunk = tid & 7;
    const int scg    = schunk ^ (srow & 7);
    const __hip_bfloat16* Ag = A  + (size_t)(m0 + srow) * K + scg * 8;
    const __hip_bfloat16* Bg = Bm + (size_t)(n0 + srow) * K + scg * 8;
    char* lA = (char*)ldsA + wv * 1024;
    char* lB = (char*)ldsB + wv * 1024;

    const int wrow  = (wv >> 1) * 64;
    const int wcol  = (wv & 1) * 64;
    const int fr    = lane & 31;
    const int khalf = lane >> 5;

    floatx16 acc[2][2] = {};

    for (int k0 = 0; k0 < K; k0 += BK) {
        #pragma unroll
        for (int s = 0; s < 4; ++s)
            gload_lds16(Ag + (size_t)(s * 32) * K + k0, lA + s * 4096);
        #pragma unroll
        for (int s = 0; s < 4; ++s)
            gload_lds16(Bg + (size_t)(s * 32) * K + k0, lB + s * 4096);
        __syncthreads();

        #pragma unroll
        for (int kk = 0; kk < 4; ++kk) {
            const int cg = kk * 2 + khalf;
            short8 af[2], bf[2];
            #pragma unroll
            for (int i = 0; i < 2; ++i) {
                const int r = wrow + i * 32 + fr;
                af[i] = *(const short8*)((const char*)ldsA + r * 128 + ((cg ^ (r & 7)) * 16));
            }
            #pragma unroll
            for (int j = 0; j < 2; ++j) {
                const int r = wcol + j * 32 + fr;
                bf[j] = *(const short8*)((const char*)ldsB + r * 128 + ((cg ^ (r & 7)) * 16));
            }
            #pragma unroll
            for (int i = 0; i < 2; ++i)
                #pragma unroll
                for (int j = 0; j < 2; ++j)
                    acc[i][j] = __builtin_amdgcn_mfma_f32_32x32x16_bf16(af[i], bf[j], acc[i][j], 0, 0, 0);
        }
        __syncthreads();
    }

    // fused LSTM epilogue.
    // C/D layout (32x32): col = lane&31, row = (reg&3) + 8*(reg>>2) + 4*(lane>>5).
    // Global col c = n0 + wcol + j*32 + fr: gate = (j*32+fr)>>4, h = (n0+wcol)/64*16 + (fr&15).
    // j=0: fr<16 -> f, fr>=16 -> i ; j=1: fr<16 -> o, fr>=16 -> g.
    const int h = ((n0 + wcol) >> 6) * 16 + (fr & 15);
    const float bfb = bxf[h];
    const float bib = bxi[h];
    const float bob = bxo[h];
    const float bgb = bxg[h];
    const bool low = (fr < 16);

    #pragma unroll
    for (int i = 0; i < 2; ++i) {
        const int row_base = m0 + wrow + i * 32 + 4 * khalf;
        #pragma unroll
        for (int reg = 0; reg < 16; ++reg) {
            const float v0 = acc[i][0][reg];
            const float v1 = acc[i][1][reg];
            const float o0 = __shfl_xor(v0, 16);
            const float o1 = __shfl_xor(v1, 16);
            const float fpre = low ? v0 : o0;
            const float ipre = low ? o0 : v0;
            const float opre = low ? v1 : o1;
            const float gpre = low ? o1 : v1;
            // split work: low lanes take regs 0..7, high lanes regs 8..15
            if (low == (reg < 8)) {
                const int row = row_base + (reg & 3) + 8 * (reg >> 2);
                const size_t off = (size_t)row * H_ + h;
                const float f  = sigmoidf_(fpre + bfb);
                const float ii = sigmoidf_(ipre + bib);
                const float o  = sigmoidf_(opre + bob);
                const float g  = tanhf_(gpre + bgb);
                const float c  = f * cell[off] + ii * g;
                const float nh = o * tanhf_(c);
                new_cell[off]   = c;
                new_hidden[off] = nh;
                hb[off] = __float2bfloat16(nh);
            }
        }
    }
}

// ---------- output GEMM: C = A * B^T + bias (fp32 out) ----------
// 128x64 tile, BK=64, 4 waves each 32x64 (acc[2]). 512 blocks = 2/CU.
__global__ __launch_bounds__(256, 2) void gemm_out(
    const __hip_bfloat16* __restrict__ A,
    const __hip_bfloat16* __restrict__ Bm,
    float* __restrict__ C,
    const float* __restrict__ bias)
{
    constexpr int BK = 64;
    constexpr int K  = 1024;
    constexpr int N  = 1024;

    __shared__ __hip_bfloat16 ldsA[128 * BK];  // 16 KB
    __shared__ __hip_bfloat16 ldsB[64 * BK];   //  8 KB

    const int tid  = threadIdx.x;
    const int lane = tid & 63;
    const int wv   = tid >> 6;

    // 512 blocks: xcd owns n-tiles [xcd*2, xcd*2+2)
    const int bid    = blockIdx.x;
    const int xcd    = bid & 7;
    const int loc    = bid >> 3;               // 0..63
    const int n_tile = xcd * 2 + (loc & 1);    // 0..15
    const int m_tile = loc >> 1;               // 0..31
    const int m0 = m_tile * 128;
    const int n0 = n_tile * 64;

    const int srow   = tid >> 3;
    const int schunk = tid & 7;
    const int scg    = schunk ^ (srow & 7);
    const __hip_bfloat16* Ag = A  + (size_t)(m0 + srow) * K + scg * 8;
    const __hip_bfloat16* Bg = Bm + (size_t)(n0 + srow) * K + scg * 8;
    char* lA = (char*)ldsA + wv * 1024;
    char* lB = (char*)ldsB + wv * 1024;

    const int wrow  = wv * 32;
    const int fr    = lane & 31;
    const int khalf = lane >> 5;

    floatx16 acc[2] = {};

    for (int k0 = 0; k0 < K; k0 += BK) {
        #pragma unroll
        for (int s = 0; s < 4; ++s)
            gload_lds16(Ag + (size_t)(s * 32) * K + k0, lA + s * 4096);
        #pragma unroll
        for (int s = 0; s < 2; ++s)
            gload_lds16(Bg + (size_t)(s * 32) * K + k0, lB + s * 4096);
        __syncthreads();

        #pragma unroll
        for (int kk = 0; kk < 4; ++kk) {
            const int cg = kk * 2 + khalf;
            const int ra = wrow + fr;
            short8 af = *(const short8*)((const char*)ldsA + ra * 128 + ((cg ^ (ra & 7)) * 16));
            short8 bf[2];
            #pragma unroll
            for (int j = 0; j < 2; ++j) {
                const int r = j * 32 + fr;
                bf[j] = *(const short8*)((const char*)ldsB + r * 128 + ((cg ^ (r & 7)) * 16));
            }
            #pragma unroll
            for (int j = 0; j < 2; ++j)
                acc[j] = __builtin_amdgcn_mfma_f32_32x32x16_bf16(af, bf[j], acc[j], 0, 0, 0);
        }
        __syncthreads();
    }

    #pragma unroll
    for (int j = 0; j < 2; ++j) {
        const int col = n0 + j * 32 + fr;
        const float bb = bias[col];
        #pragma unroll
        for (int reg = 0; reg < 16; ++reg) {
            const int row = m0 + wrow + 4 * khalf + (reg & 3) + 8 * (reg >> 2);
            C[(size_t)row * N + col] = acc[j][reg] + bb;
        }
    }
}

// ---------- launch ----------
extern "C" void kernel_launch(void* const* d_in, const int* in_sizes, int n_in,
                              void* d_out, int out_size, void* d_ws, size_t ws_size,
                              hipStream_t stream) {
    const float* input_vec  = (const float*)d_in[0];
    const float* hidden_vec = (const float*)d_in[1];
    const float* cell_vec   = (const float*)d_in[2];
    const float* Wx_f = (const float*)d_in[3];
    const float* bx_f = (const float*)d_in[4];
    const float* Wh_f = (const float*)d_in[5];
    const float* Wx_i = (const float*)d_in[6];
    const float* bx_i = (const float*)d_in[7];
    const float* Wh_i = (const float*)d_in[8];
    const float* Wx_o = (const float*)d_in[9];
    const float* bx_o = (const float*)d_in[10];
    const float* Wh_o = (const float*)d_in[11];
    const float* Wx_g = (const float*)d_in[12];
    const float* bx_g = (const float*)d_in[13];
    const float* Wh_g = (const float*)d_in[14];
    const float* W_out = (const float*)d_in[15];
    const float* b_out = (const float*)d_in[16];

    char* ws = (char*)d_ws;
    __hip_bfloat16* xh  = (__hip_bfloat16*)(ws);                        // 16 MB [4096][2048]
    __hip_bfloat16* Wc  = (__hip_bfloat16*)(ws + (16ull << 20));        // 16 MB [4096][2048]
    __hip_bfloat16* Wob = (__hip_bfloat16*)(ws + (32ull << 20));        //  2 MB [1024][1024]
    __hip_bfloat16* hb  = (__hip_bfloat16*)(ws + (34ull << 20));        //  8 MB [4096][1024]

    float* new_hidden = (float*)d_out;
    float* new_cell   = new_hidden + (size_t)B_ * H_;
    float* out_vec    = new_cell + (size_t)B_ * H_;

    Ptrs8 p;
    p.p[0] = Wx_f; p.p[1] = Wh_f; p.p[2] = Wx_i; p.p[3] = Wh_i;
    p.p[4] = Wx_o; p.p[5] = Wh_o; p.p[6] = Wx_g; p.p[7] = Wh_g;
    cvt_all_kernel<<<17408, 256, 0, stream>>>(input_vec, hidden_vec, p, W_out, xh, Wc, Wob);

    // gates GEMM + fused gating: writes new_hidden, new_cell (fp32) and hb (bf16)
    gemm_gate_fused<<<1024, 256, 0, stream>>>(
        xh, Wc, cell_vec, bx_f, bx_i, bx_o, bx_g, new_hidden, new_cell, hb);

    // output_vec = new_hidden @ W_out^T + b_out
    gemm_out<<<512, 256, 0, stream>>>(hb, Wob, out_vec, b_out);
}

// Round 6
// 242.481 us; speedup vs baseline: 1.1006x; 1.1006x over previous
//
#include <hip/hip_runtime.h>
#include <hip/hip_bf16.h>
#include <stdint.h>

#define B_   4096
#define IN_  1024
#define H_   1024
#define OUT_ 1024

typedef __attribute__((ext_vector_type(8)))  short short8;
typedef __attribute__((ext_vector_type(16))) float floatx16;

// ---------- async global->LDS (16B per lane; LDS base wave-uniform, HW adds lane*16) ----------
__device__ static inline void gload_lds16(const void* g, void* l) {
    __builtin_amdgcn_global_load_lds(
        (const __attribute__((address_space(1))) unsigned int*)g,
        (__attribute__((address_space(3))) unsigned int*)l,
        16, 0, 0);
}

__device__ static inline float sigmoidf_(float x) { return 1.0f / (1.0f + __expf(-x)); }
__device__ static inline float tanhf_(float x)    { return 1.0f - 2.0f / (1.0f + __expf(2.0f * x)); }

// ---------- merged conversion kernel ----------
// blocks [0,8192):    xh[b][c] = bf16(c<1024 ? x[b][c] : h[b][c-1024])        [4096][2048]
// blocks [8192,16384): Wc gate-block interleaved period 128: n = (h>>5)*128 + gate*32 + (h&31)
// blocks [16384,17408): Wob = bf16(W_out)                                     [1024][1024]
struct Ptrs8 { const float* p[8]; };

__global__ void cvt_all_kernel(const float* __restrict__ x, const float* __restrict__ h,
                               Ptrs8 ptrs, const float* __restrict__ wout,
                               __hip_bfloat16* __restrict__ xh,
                               __hip_bfloat16* __restrict__ Wc,
                               __hip_bfloat16* __restrict__ Wob) {
    int blk = blockIdx.x;
    const float* src;
    __hip_bfloat16* dst;
    if (blk < 8192) {
        int idx = blk * 256 + threadIdx.x;          // B*512
        int b  = idx >> 9;
        int c4 = (idx & 511) * 4;
        src = (c4 < IN_) ? (x + (size_t)b * IN_ + c4)
                         : (h + (size_t)b * H_ + (c4 - IN_));
        dst = xh + (size_t)b * 2048 + c4;
    } else if (blk < 16384) {
        int idx = (blk - 8192) * 256 + threadIdx.x; // 4096*512
        int n  = idx >> 9;
        int c4 = (idx & 511) * 4;
        int gate = (n >> 5) & 3;
        int hh   = ((n >> 7) << 5) + (n & 31);
        src = (c4 < 1024) ? (ptrs.p[2 * gate]     + (size_t)hh * 1024 + c4)
                          : (ptrs.p[2 * gate + 1] + (size_t)hh * 1024 + (c4 - 1024));
        dst = Wc + (size_t)n * 2048 + c4;
    } else {
        int idx = (blk - 16384) * 256 + threadIdx.x;
        src = wout + (size_t)idx * 4;
        dst = Wob + (size_t)idx * 4;
    }
    float4 v = *(const float4*)src;
    dst[0] = __float2bfloat16(v.x);
    dst[1] = __float2bfloat16(v.y);
    dst[2] = __float2bfloat16(v.z);
    dst[3] = __float2bfloat16(v.w);
}

// ---------- gate GEMM + fused LSTM epilogue (R4 measured-best: 89 us, 772 TF) ----------
// A = xh [4096][2048], Bm = Wc [4096][2048] (gate-block interleaved, period 128).
// Block tile 256x128, BK=64. 4 waves, each 64 rows x 128 cols: acc[2][4].
// 85 MACs per staged byte; 512 cyc MFMA per barrier per wave-pair. WC=1 keeps the
// whole gate set of an h column in one lane -> branch-free epilogue, no cross-lane.
__global__ __launch_bounds__(256, 2) void gemm_gate_fused(
    const __hip_bfloat16* __restrict__ A,
    const __hip_bfloat16* __restrict__ Bm,
    const float* __restrict__ cell,
    const float* __restrict__ bxf, const float* __restrict__ bxi,
    const float* __restrict__ bxo, const float* __restrict__ bxg,
    float* __restrict__ new_hidden, float* __restrict__ new_cell,
    __hip_bfloat16* __restrict__ hb)
{
    constexpr int BK = 64;
    constexpr int K  = 2048;

    __shared__ __hip_bfloat16 ldsA[256 * BK];   // 32 KB
    __shared__ __hip_bfloat16 ldsB[128 * BK];   // 16 KB

    const int tid  = threadIdx.x;
    const int lane = tid & 63;
    const int wv   = tid >> 6;

    // XCD swizzle: xcd = bid&7 owns n-tiles [xcd*4, xcd*4+4) (2MB Wc stripe -> its L2).
    const int bid    = blockIdx.x;             // 512 blocks
    const int xcd    = bid & 7;
    const int loc    = bid >> 3;               // 0..63
    const int n_tile = xcd * 4 + (loc & 3);    // 0..31
    const int m_tile = loc >> 2;               // 0..15
    const int m0 = m_tile * 256;
    const int n0 = n_tile * 128;

    // staging gather: thread tid fills LDS slot tid*16 (+s*4096 per issue);
    // row = s*32 + tid/8, stored chunk = tid%8 -> fetch global chunk (tid%8)^(row&7)
    const int srow   = tid >> 3;
    const int schunk = tid & 7;
    const int scg    = schunk ^ (srow & 7);
    const __hip_bfloat16* Ag = A  + (size_t)(m0 + srow) * K + scg * 8;
    const __hip_bfloat16* Bg = Bm + (size_t)(n0 + srow) * K + scg * 8;
    char* lA = (char*)ldsA + wv * 1024;
    char* lB = (char*)ldsB + wv * 1024;

    const int wrow  = wv * 64;                 // wave's 64-row band
    const int fr    = lane & 31;
    const int khalf = lane >> 5;

    floatx16 acc[2][4] = {};                   // [row half][gate]

    for (int k0 = 0; k0 < K; k0 += BK) {
        #pragma unroll
        for (int s = 0; s < 8; ++s)
            gload_lds16(Ag + (size_t)(s * 32) * K + k0, lA + s * 4096);
        #pragma unroll
        for (int s = 0; s < 4; ++s)
            gload_lds16(Bg + (size_t)(s * 32) * K + k0, lB + s * 4096);
        __syncthreads();

        #pragma unroll
        for (int kk = 0; kk < 4; ++kk) {
            const int cg = kk * 2 + khalf;
            short8 af[2], bf[4];
            #pragma unroll
            for (int i = 0; i < 2; ++i) {
                const int r = wrow + i * 32 + fr;
                af[i] = *(const short8*)((const char*)ldsA + r * 128 + ((cg ^ (r & 7)) * 16));
            }
            #pragma unroll
            for (int j = 0; j < 4; ++j) {
                const int r = j * 32 + fr;
                bf[j] = *(const short8*)((const char*)ldsB + r * 128 + ((cg ^ (r & 7)) * 16));
            }
            #pragma unroll
            for (int i = 0; i < 2; ++i)
                #pragma unroll
                for (int j = 0; j < 4; ++j)
                    acc[i][j] = __builtin_amdgcn_mfma_f32_32x32x16_bf16(af[i], bf[j], acc[i][j], 0, 0, 0);
        }
        __syncthreads();
    }

    // fused LSTM epilogue.
    // C/D layout (32x32): col = lane&31, row = (reg&3) + 8*(reg>>2) + 4*(lane>>5).
    // col j*32+fr = gate j of h = n_tile*32 + fr. Lane owns all 4 gates of its h.
    const int h  = (n0 >> 2) + fr;
    const float bfb = bxf[h];
    const float bib = bxi[h];
    const float bob = bxo[h];
    const float bgb = bxg[h];

    #pragma unroll
    for (int i = 0; i < 2; ++i) {
        const int row_base = m0 + wrow + i * 32 + 4 * khalf;
        #pragma unroll
        for (int reg = 0; reg < 16; ++reg) {
            const int row = row_base + (reg & 3) + 8 * (reg >> 2);
            const size_t off = (size_t)row * H_ + h;
            const float f = sigmoidf_(acc[i][0][reg] + bfb);
            const float ii = sigmoidf_(acc[i][1][reg] + bib);
            const float o = sigmoidf_(acc[i][2][reg] + bob);
            const float g = tanhf_(acc[i][3][reg] + bgb);
            const float c = f * cell[off] + ii * g;
            const float nh = o * tanhf_(c);
            new_cell[off]   = c;
            new_hidden[off] = nh;
            hb[off] = __float2bfloat16(nh);
        }
    }
}

// ---------- output GEMM (R3 measured-best config): C = A * B^T + bias ----------
// 128x64 tile, BK=64, 4 waves each 32x64 (acc[2]). 512 blocks = 2/CU.
__global__ __launch_bounds__(256, 2) void gemm_out(
    const __hip_bfloat16* __restrict__ A,
    const __hip_bfloat16* __restrict__ Bm,
    float* __restrict__ C,
    const float* __restrict__ bias)
{
    constexpr int BK = 64;
    constexpr int K  = 1024;
    constexpr int N  = 1024;

    __shared__ __hip_bfloat16 ldsA[128 * BK];  // 16 KB
    __shared__ __hip_bfloat16 ldsB[64 * BK];   //  8 KB

    const int tid  = threadIdx.x;
    const int lane = tid & 63;
    const int wv   = tid >> 6;

    // 512 blocks: xcd owns n-tiles [xcd*2, xcd*2+2)
    const int bid    = blockIdx.x;
    const int xcd    = bid & 7;
    const int loc    = bid >> 3;               // 0..63
    const int n_tile = xcd * 2 + (loc & 1);    // 0..15
    const int m_tile = loc >> 1;               // 0..31
    const int m0 = m_tile * 128;
    const int n0 = n_tile * 64;

    const int srow   = tid >> 3;
    const int schunk = tid & 7;
    const int scg    = schunk ^ (srow & 7);
    const __hip_bfloat16* Ag = A  + (size_t)(m0 + srow) * K + scg * 8;
    const __hip_bfloat16* Bg = Bm + (size_t)(n0 + srow) * K + scg * 8;
    char* lA = (char*)ldsA + wv * 1024;
    char* lB = (char*)ldsB + wv * 1024;

    const int wrow  = wv * 32;
    const int fr    = lane & 31;
    const int khalf = lane >> 5;

    floatx16 acc[2] = {};

    for (int k0 = 0; k0 < K; k0 += BK) {
        #pragma unroll
        for (int s = 0; s < 4; ++s)
            gload_lds16(Ag + (size_t)(s * 32) * K + k0, lA + s * 4096);
        #pragma unroll
        for (int s = 0; s < 2; ++s)
            gload_lds16(Bg + (size_t)(s * 32) * K + k0, lB + s * 4096);
        __syncthreads();

        #pragma unroll
        for (int kk = 0; kk < 4; ++kk) {
            const int cg = kk * 2 + khalf;
            const int ra = wrow + fr;
            short8 af = *(const short8*)((const char*)ldsA + ra * 128 + ((cg ^ (ra & 7)) * 16));
            short8 bf[2];
            #pragma unroll
            for (int j = 0; j < 2; ++j) {
                const int r = j * 32 + fr;
                bf[j] = *(const short8*)((const char*)ldsB + r * 128 + ((cg ^ (r & 7)) * 16));
            }
            #pragma unroll
            for (int j = 0; j < 2; ++j)
                acc[j] = __builtin_amdgcn_mfma_f32_32x32x16_bf16(af, bf[j], acc[j], 0, 0, 0);
        }
        __syncthreads();
    }

    #pragma unroll
    for (int j = 0; j < 2; ++j) {
        const int col = n0 + j * 32 + fr;
        const float bb = bias[col];
        #pragma unroll
        for (int reg = 0; reg < 16; ++reg) {
            const int row = m0 + wrow + 4 * khalf + (reg & 3) + 8 * (reg >> 2);
            C[(size_t)row * N + col] = acc[j][reg] + bb;
        }
    }
}

// ---------- launch ----------
extern "C" void kernel_launch(void* const* d_in, const int* in_sizes, int n_in,
                              void* d_out, int out_size, void* d_ws, size_t ws_size,
                              hipStream_t stream) {
    const float* input_vec  = (const float*)d_in[0];
    const float* hidden_vec = (const float*)d_in[1];
    const float* cell_vec   = (const float*)d_in[2];
    const float* Wx_f = (const float*)d_in[3];
    const float* bx_f = (const float*)d_in[4];
    const float* Wh_f = (const float*)d_in[5];
    const float* Wx_i = (const float*)d_in[6];
    const float* bx_i = (const float*)d_in[7];
    const float* Wh_i = (const float*)d_in[8];
    const float* Wx_o = (const float*)d_in[9];
    const float* bx_o = (const float*)d_in[10];
    const float* Wh_o = (const float*)d_in[11];
    const float* Wx_g = (const float*)d_in[12];
    const float* bx_g = (const float*)d_in[13];
    const float* Wh_g = (const float*)d_in[14];
    const float* W_out = (const float*)d_in[15];
    const float* b_out = (const float*)d_in[16];

    char* ws = (char*)d_ws;
    __hip_bfloat16* xh  = (__hip_bfloat16*)(ws);                        // 16 MB [4096][2048]
    __hip_bfloat16* Wc  = (__hip_bfloat16*)(ws + (16ull << 20));        // 16 MB [4096][2048]
    __hip_bfloat16* Wob = (__hip_bfloat16*)(ws + (32ull << 20));        //  2 MB [1024][1024]
    __hip_bfloat16* hb  = (__hip_bfloat16*)(ws + (34ull << 20));        //  8 MB [4096][1024]

    float* new_hidden = (float*)d_out;
    float* new_cell   = new_hidden + (size_t)B_ * H_;
    float* out_vec    = new_cell + (size_t)B_ * H_;

    Ptrs8 p;
    p.p[0] = Wx_f; p.p[1] = Wh_f; p.p[2] = Wx_i; p.p[3] = Wh_i;
    p.p[4] = Wx_o; p.p[5] = Wh_o; p.p[6] = Wx_g; p.p[7] = Wh_g;
    cvt_all_kernel<<<17408, 256, 0, stream>>>(input_vec, hidden_vec, p, W_out, xh, Wc, Wob);

    // gates GEMM + fused gating: writes new_hidden, new_cell (fp32) and hb (bf16)
    gemm_gate_fused<<<512, 256, 0, stream>>>(
        xh, Wc, cell_vec, bx_f, bx_i, bx_o, bx_g, new_hidden, new_cell, hb);

    // output_vec = new_hidden @ W_out^T + b_out
    gemm_out<<<512, 256, 0, stream>>>(hb, Wob, out_vec, b_out);
}